// Round 2
// baseline (1202.609 us; speedup 1.0000x reference)
//
#include <hip/hip_runtime.h>

#define D 2048
#define I_DIM 1408
#define E_NUM 16
#define NTOK 8192
#define BK 32
#define BK2 64

typedef _Float16 half8 __attribute__((ext_vector_type(8)));
typedef float float4v __attribute__((ext_vector_type(4)));

// async global->LDS, 16B per lane; LDS dest = base + lane*16 (linear!)
#define GLL16(gp, lp)                                                        \
    __builtin_amdgcn_global_load_lds(                                        \
        (const __attribute__((address_space(1))) void*)(gp),                 \
        (__attribute__((address_space(3))) void*)(lp), 16, 0, 0)

// ---------------- fast-path workspace layout (bytes) ----------------
// counts @0 (1024) | ids @1024 (512K) | wts @525312 (512K) | wtk @1049600 (64K)
// xb @1115136 (32M) | h @34669568 (44M) | wgt @80806912 (88M) | wut @173081600 (88M)
// wdt aliases wgt (used after gateup) | part aliases wut (used after gateup)
// FAST_NEED = 265356288

// ---------------- router ----------------
__global__ __launch_bounds__(256) void router_kernel(
    const float* __restrict__ x, const float* __restrict__ gw,
    _Float16* __restrict__ xb, int* __restrict__ counts,
    int* __restrict__ ids, float* __restrict__ wts, float* __restrict__ wtk)
{
    int t = blockIdx.x * 4 + (threadIdx.x >> 6);
    int lane = threadIdx.x & 63;
    const float* xr = x + (size_t)t * D;

    float acc[E_NUM];
#pragma unroll
    for (int e = 0; e < E_NUM; ++e) acc[e] = 0.f;

#pragma unroll 4
    for (int i = 0; i < D / 64; ++i) {
        int d = lane + i * 64;
        float xv = xr[d];
        xb[(size_t)t * D + d] = (_Float16)xv;
#pragma unroll
        for (int e = 0; e < E_NUM; ++e)
            acc[e] = fmaf(xv, gw[e * D + d], acc[e]);
    }
#pragma unroll
    for (int e = 0; e < E_NUM; ++e) {
        float v = acc[e];
#pragma unroll
        for (int m = 32; m >= 1; m >>= 1) v += __shfl_xor(v, m, 64);
        acc[e] = v;
    }
    if (lane == 0) {
        int e1 = 0; float l1 = acc[0];
#pragma unroll
        for (int e = 1; e < E_NUM; ++e)
            if (acc[e] > l1) { l1 = acc[e]; e1 = e; }
        int e2 = -1; float l2 = -3.0e38f;
#pragma unroll
        for (int e = 0; e < E_NUM; ++e) {
            if (e == e1) continue;
            if (acc[e] > l2) { l2 = acc[e]; e2 = e; }
        }
        float w1 = 1.f / (1.f + expf(l2 - l1));
        float w2 = 1.f - w1;
        int s1 = atomicAdd(&counts[e1], 1);
        ids[e1 * NTOK + s1] = t * 2;     wts[e1 * NTOK + s1] = w1;
        int s2 = atomicAdd(&counts[e2], 1);
        ids[e2 * NTOK + s2] = t * 2 + 1; wts[e2 * NTOK + s2] = w2;
        wtk[t * 2] = w1; wtk[t * 2 + 1] = w2;
    }
}

// ---------------- transpose+convert: src fp32 [E][K][N] -> dst fp16 [E][N][K] ----------------
// fp32 LDS tile [64][65]: +1 pad makes both the transposed scatter (write) and the
// row read 2-way bank accesses (free). Convert fp32->fp16 at read time.
__global__ __launch_bounds__(256) void transpose_cvt_kernel(
    const float* __restrict__ src, _Float16* __restrict__ dst, int K, int N)
{
    int e = blockIdx.z;
    int k0 = blockIdx.x * 64;
    int n0 = blockIdx.y * 64;
    const float* s = src + (size_t)e * K * N + (size_t)k0 * N + n0;
    _Float16* d = dst + (size_t)e * N * K + (size_t)n0 * K + k0;

    __shared__ float T[64][65];
    int tid = threadIdx.x;
    int kl = tid >> 4;          // 0..15
    int n4 = (tid & 15) * 4;    // 0..60
#pragma unroll
    for (int p = 0; p < 4; ++p) {
        int k = p * 16 + kl;
        float4 v = *(const float4*)(s + (size_t)k * N + n4);
        T[n4 + 0][k] = v.x;     // transposed scatter into [n][k]
        T[n4 + 1][k] = v.y;
        T[n4 + 2][k] = v.z;
        T[n4 + 3][k] = v.w;
    }
    __syncthreads();
    int nl = tid >> 3;          // 0..31
    int kc = (tid & 7) * 8;     // 0..56
#pragma unroll
    for (int q = 0; q < 2; ++q) {
        int n = q * 32 + nl;
        half8 v;
#pragma unroll
        for (int j = 0; j < 8; ++j) v[j] = (_Float16)T[n][kc + j];
        *(half8*)(d + (size_t)n * K + kc) = v;
    }
}

// ---------------- fast gate+up: BK2=64, XOR-swizzled LDS (linear dest + pre-swizzled src) ----------------
// LDS(row, seg) holds global(row, seg ^ (row&7)); read applies the same XOR -> banks spread
// across all 8 quad-groups, 2-way max (free). Row stride 128B.
__global__ __launch_bounds__(256, 2) void moe_gateup_f16(
    const _Float16* __restrict__ xb,
    const _Float16* __restrict__ wgt, const _Float16* __restrict__ wut,
    const int* __restrict__ counts, const int* __restrict__ ids,
    _Float16* __restrict__ h)
{
    int b = blockIdx.x;
    int g = b % 176;                 // n_tile (11) x expert (16)
    int m0 = (b / 176) * 128;        // groups spaced 176 apart -> same XCD
    int e = g / 11;
    int n0 = (g % 11) * 128;
    int cnt = counts[e];
    if (m0 >= cnt) return;

    __shared__ __align__(16) _Float16 Als[128 * BK2];
    __shared__ __align__(16) _Float16 Bg[128 * BK2];
    __shared__ __align__(16) _Float16 Bu[128 * BK2];
    __shared__ int rid[128];

    int tid = threadIdx.x;
    if (tid < 128) {
        int slot = m0 + tid;
        rid[tid] = (slot < cnt) ? ids[e * NTOK + slot] : -1;
    }
    __syncthreads();

    const _Float16* wgE = wgt + (size_t)e * I_DIM * D;
    const _Float16* wuE = wut + (size_t)e * I_DIM * D;

    int wave = tid >> 6, lane = tid & 63;
    int wm = (wave & 1) * 64, wn = (wave >> 1) * 64;
    int lc = lane & 15, lq = lane >> 4;
    int lr8 = lane >> 3;                     // sub-row 0..7 within an 8-row chunk
    int gseg = ((lane & 7) ^ lr8) * 8;       // swizzled source offset (halves)

    float4v accG[4][4], accU[4][4];
#pragma unroll
    for (int a = 0; a < 4; ++a)
#pragma unroll
        for (int c = 0; c < 4; ++c) {
            accG[a][c] = (float4v){0.f, 0.f, 0.f, 0.f};
            accU[a][c] = (float4v){0.f, 0.f, 0.f, 0.f};
        }

    for (int k0 = 0; k0 < D; k0 += BK2) {
#pragma unroll
        for (int c = 0; c < 4; ++c) {
            int r0 = wave * 32 + c * 8;      // wave-uniform LDS base (8 rows = 1KB)
            int row = r0 + lr8;
            int id = rid[row];
            int tr = (id >= 0) ? (id >> 1) : 0;
            GLL16(xb + (size_t)tr * D + k0 + gseg, &Als[r0 * BK2]);
            GLL16(wgE + (size_t)(n0 + row) * D + k0 + gseg, &Bg[r0 * BK2]);
            GLL16(wuE + (size_t)(n0 + row) * D + k0 + gseg, &Bu[r0 * BK2]);
        }
        __syncthreads();

#pragma unroll
        for (int ks = 0; ks < 2; ++ks) {
            half8 af[4];
#pragma unroll
            for (int ms = 0; ms < 4; ++ms) {
                int row = wm + ms * 16 + lc;
                int s = (ks * 4 + lq) ^ (row & 7);
                af[ms] = *(const half8*)(&Als[row * BK2 + s * 8]);
            }
#pragma unroll
            for (int ns = 0; ns < 4; ++ns) {
                int row = wn + ns * 16 + lc;
                int s = (ks * 4 + lq) ^ (row & 7);
                half8 bg = *(const half8*)(&Bg[row * BK2 + s * 8]);
                half8 bu = *(const half8*)(&Bu[row * BK2 + s * 8]);
#pragma unroll
                for (int ms = 0; ms < 4; ++ms) {
                    accG[ms][ns] = __builtin_amdgcn_mfma_f32_16x16x32_f16(af[ms], bg, accG[ms][ns], 0, 0, 0);
                    accU[ms][ns] = __builtin_amdgcn_mfma_f32_16x16x32_f16(af[ms], bu, accU[ms][ns], 0, 0, 0);
                }
            }
        }
        __syncthreads();
    }

#pragma unroll
    for (int ms = 0; ms < 4; ++ms) {
#pragma unroll
        for (int r = 0; r < 4; ++r) {
            int row = wm + ms * 16 + lq * 4 + r;
            int id = rid[row];
            if (id >= 0) {
                _Float16* hr = h + (size_t)id * I_DIM + n0;
#pragma unroll
                for (int ns = 0; ns < 4; ++ns) {
                    float gv = accG[ms][ns][r];
                    float uv = accU[ms][ns][r];
                    float sv = gv / (1.f + expf(-gv)) * uv;
                    hr[wn + ns * 16 + lc] = (_Float16)sv;
                }
            }
        }
    }
}

// ---------------- fast down: BK2=64, same swizzle ----------------
__global__ __launch_bounds__(256, 2) void moe_down_f16(
    const _Float16* __restrict__ h, const _Float16* __restrict__ wdt,
    const int* __restrict__ counts, const int* __restrict__ ids,
    _Float16* __restrict__ part)
{
    int b = blockIdx.x;
    int g = b % 256;                 // n_tile (16) x expert (16)
    int m0 = (b / 256) * 128;        // spaced 256 apart -> same XCD
    int e = g >> 4;
    int n0 = (g & 15) * 128;
    int cnt = counts[e];
    if (m0 >= cnt) return;

    __shared__ __align__(16) _Float16 Als[128 * BK2];
    __shared__ __align__(16) _Float16 Bd[128 * BK2];
    __shared__ int rid[128];

    int tid = threadIdx.x;
    if (tid < 128) {
        int slot = m0 + tid;
        rid[tid] = (slot < cnt) ? ids[e * NTOK + slot] : -1;
    }
    __syncthreads();

    const _Float16* wdE = wdt + (size_t)e * D * I_DIM;

    int wave = tid >> 6, lane = tid & 63;
    int wm = (wave & 1) * 64, wn = (wave >> 1) * 64;
    int lc = lane & 15, lq = lane >> 4;
    int lr8 = lane >> 3;
    int gseg = ((lane & 7) ^ lr8) * 8;

    float4v acc[4][4];
#pragma unroll
    for (int a = 0; a < 4; ++a)
#pragma unroll
        for (int c = 0; c < 4; ++c)
            acc[a][c] = (float4v){0.f, 0.f, 0.f, 0.f};

    for (int k0 = 0; k0 < I_DIM; k0 += BK2) {
#pragma unroll
        for (int c = 0; c < 4; ++c) {
            int r0 = wave * 32 + c * 8;
            int row = r0 + lr8;
            int id = rid[row];
            int tr = (id >= 0) ? id : 0;
            GLL16(h + (size_t)tr * I_DIM + k0 + gseg, &Als[r0 * BK2]);
            GLL16(wdE + (size_t)(n0 + row) * I_DIM + k0 + gseg, &Bd[r0 * BK2]);
        }
        __syncthreads();

#pragma unroll
        for (int ks = 0; ks < 2; ++ks) {
            half8 af[4];
#pragma unroll
            for (int ms = 0; ms < 4; ++ms) {
                int row = wm + ms * 16 + lc;
                int s = (ks * 4 + lq) ^ (row & 7);
                af[ms] = *(const half8*)(&Als[row * BK2 + s * 8]);
            }
#pragma unroll
            for (int ns = 0; ns < 4; ++ns) {
                int row = wn + ns * 16 + lc;
                int s = (ks * 4 + lq) ^ (row & 7);
                half8 bd = *(const half8*)(&Bd[row * BK2 + s * 8]);
#pragma unroll
                for (int ms = 0; ms < 4; ++ms)
                    acc[ms][ns] = __builtin_amdgcn_mfma_f32_16x16x32_f16(af[ms], bd, acc[ms][ns], 0, 0, 0);
            }
        }
        __syncthreads();
    }

#pragma unroll
    for (int ms = 0; ms < 4; ++ms) {
#pragma unroll
        for (int r = 0; r < 4; ++r) {
            int row = wm + ms * 16 + lq * 4 + r;
            int id = rid[row];
            if (id >= 0) {
                _Float16* pr = part + (size_t)id * D + n0;
#pragma unroll
                for (int ns = 0; ns < 4; ++ns)
                    pr[wn + ns * 16 + lc] = (_Float16)acc[ms][ns][r];
            }
        }
    }
}

// ---------------- combine: out[t] = w1*part[2t] + w2*part[2t+1] ----------------
__global__ __launch_bounds__(256) void combine_kernel(
    const _Float16* __restrict__ part, const float* __restrict__ wtk,
    float* __restrict__ out)
{
    int t = blockIdx.x;
    int tid = threadIdx.x;
    float w1 = wtk[2 * t], w2 = wtk[2 * t + 1];
    const _Float16* p1 = part + (size_t)(2 * t) * D;
    const _Float16* p2 = p1 + D;
    float* o = out + (size_t)t * D;
    int i = tid * 8;
    half8 a = *(const half8*)(p1 + i);
    half8 bvec = *(const half8*)(p2 + i);
#pragma unroll
    for (int j = 0; j < 8; ++j)
        o[i + j] = w1 * (float)a[j] + w2 * (float)bvec[j];
}

// ================= fallback (round-1) kernels, fp32 weights =================
__global__ __launch_bounds__(256, 2) void moe_gateup_old(
    const _Float16* __restrict__ xb,
    const float* __restrict__ wg, const float* __restrict__ wu,
    const int* __restrict__ counts, const int* __restrict__ ids,
    _Float16* __restrict__ h)
{
    int e = blockIdx.z;
    int cnt = counts[e];
    int m0 = blockIdx.x * 128;
    if (m0 >= cnt) return;
    int n0 = blockIdx.y * 128;

    __shared__ __align__(16) _Float16 Als[128 * BK];
    __shared__ __align__(16) _Float16 Bg[BK * 128];
    __shared__ __align__(16) _Float16 Bu[BK * 128];
    __shared__ int rid[128];

    int tid = threadIdx.x;
    if (tid < 128) {
        int slot = m0 + tid;
        rid[tid] = (slot < cnt) ? ids[e * NTOK + slot] : -1;
    }
    __syncthreads();

    const float* wgE = wg + (size_t)e * D * I_DIM;
    const float* wuE = wu + (size_t)e * D * I_DIM;

    int wave = tid >> 6, lane = tid & 63;
    int wm = (wave & 1) * 64, wn = (wave >> 1) * 64;
    int lc = lane & 15, lq = lane >> 4;

    float4v accG[4][4], accU[4][4];
#pragma unroll
    for (int a = 0; a < 4; ++a)
#pragma unroll
        for (int c = 0; c < 4; ++c) {
            accG[a][c] = (float4v){0.f, 0.f, 0.f, 0.f};
            accU[a][c] = (float4v){0.f, 0.f, 0.f, 0.f};
        }

    int nn = tid & 127;
    int kb2 = tid >> 7;

    for (int k0 = 0; k0 < D; k0 += BK) {
#pragma unroll
        for (int cc = 0; cc < 2; ++cc) {
            int c = tid + cc * 256;
            int row = c >> 2, kc = c & 3;
            int id = rid[row];
            uint4 v = {0u, 0u, 0u, 0u};
            if (id >= 0)
                v = *(const uint4*)(xb + (size_t)(id >> 1) * D + k0 + kc * 8);
            *(uint4*)(&Als[row * BK + kc * 8]) = v;
        }
#pragma unroll
        for (int kk = 0; kk < 2; ++kk) {
            int kb = kb2 * 2 + kk;
            const float* pg = wgE + (size_t)(k0 + kb * 8) * I_DIM + n0 + nn;
            const float* pu = wuE + (size_t)(k0 + kb * 8) * I_DIM + n0 + nn;
            half8 hg, hu;
#pragma unroll
            for (int j = 0; j < 8; ++j) {
                hg[j] = (_Float16)pg[(size_t)j * I_DIM];
                hu[j] = (_Float16)pu[(size_t)j * I_DIM];
            }
            *(half8*)(&Bg[(kb * 128 + nn) * 8]) = hg;
            *(half8*)(&Bu[(kb * 128 + nn) * 8]) = hu;
        }
        __syncthreads();

        half8 af[4];
#pragma unroll
        for (int ms = 0; ms < 4; ++ms)
            af[ms] = *(const half8*)(&Als[(wm + ms * 16 + lc) * BK + lq * 8]);
#pragma unroll
        for (int ns = 0; ns < 4; ++ns) {
            half8 bg = *(const half8*)(&Bg[(lq * 128 + wn + ns * 16 + lc) * 8]);
            half8 bu = *(const half8*)(&Bu[(lq * 128 + wn + ns * 16 + lc) * 8]);
#pragma unroll
            for (int ms = 0; ms < 4; ++ms) {
                accG[ms][ns] = __builtin_amdgcn_mfma_f32_16x16x32_f16(af[ms], bg, accG[ms][ns], 0, 0, 0);
                accU[ms][ns] = __builtin_amdgcn_mfma_f32_16x16x32_f16(af[ms], bu, accU[ms][ns], 0, 0, 0);
            }
        }
        __syncthreads();
    }

#pragma unroll
    for (int ms = 0; ms < 4; ++ms) {
#pragma unroll
        for (int r = 0; r < 4; ++r) {
            int row = wm + ms * 16 + lq * 4 + r;
            int id = rid[row];
            if (id >= 0) {
                _Float16* hr = h + (size_t)id * I_DIM + n0;
#pragma unroll
                for (int ns = 0; ns < 4; ++ns) {
                    float gv = accG[ms][ns][r];
                    float uv = accU[ms][ns][r];
                    float sv = gv / (1.f + expf(-gv)) * uv;
                    hr[wn + ns * 16 + lc] = (_Float16)sv;
                }
            }
        }
    }
}

__global__ __launch_bounds__(256, 2) void moe_down_old(
    const _Float16* __restrict__ h, const float* __restrict__ wd,
    const int* __restrict__ counts, const int* __restrict__ ids,
    const float* __restrict__ wts, float* __restrict__ out)
{
    int e = blockIdx.z;
    int cnt = counts[e];
    int m0 = blockIdx.x * 128;
    if (m0 >= cnt) return;
    int n0 = blockIdx.y * 128;

    __shared__ __align__(16) _Float16 Als[128 * BK];
    __shared__ __align__(16) _Float16 Bd[BK * 128];
    __shared__ int rid[128];
    __shared__ float rw[128];

    int tid = threadIdx.x;
    if (tid < 128) {
        int slot = m0 + tid;
        int ok = slot < cnt;
        rid[tid] = ok ? ids[e * NTOK + slot] : -1;
        rw[tid]  = ok ? wts[e * NTOK + slot] : 0.f;
    }
    __syncthreads();

    const float* wdE = wd + (size_t)e * I_DIM * D;

    int wave = tid >> 6, lane = tid & 63;
    int wm = (wave & 1) * 64, wn = (wave >> 1) * 64;
    int lc = lane & 15, lq = lane >> 4;

    float4v acc[4][4];
#pragma unroll
    for (int a = 0; a < 4; ++a)
#pragma unroll
        for (int c = 0; c < 4; ++c)
            acc[a][c] = (float4v){0.f, 0.f, 0.f, 0.f};

    int nn = tid & 127;
    int kb2 = tid >> 7;

    for (int k0 = 0; k0 < I_DIM; k0 += BK) {
#pragma unroll
        for (int cc = 0; cc < 2; ++cc) {
            int c = tid + cc * 256;
            int row = c >> 2, kc = c & 3;
            int id = rid[row];
            uint4 v = {0u, 0u, 0u, 0u};
            if (id >= 0)
                v = *(const uint4*)(h + (size_t)id * I_DIM + k0 + kc * 8);
            *(uint4*)(&Als[row * BK + kc * 8]) = v;
        }
#pragma unroll
        for (int kk = 0; kk < 2; ++kk) {
            int kb = kb2 * 2 + kk;
            const float* pd = wdE + (size_t)(k0 + kb * 8) * D + n0 + nn;
            half8 hd;
#pragma unroll
            for (int j = 0; j < 8; ++j)
                hd[j] = (_Float16)pd[(size_t)j * D];
            *(half8*)(&Bd[(kb * 128 + nn) * 8]) = hd;
        }
        __syncthreads();

        half8 af[4];
#pragma unroll
        for (int ms = 0; ms < 4; ++ms)
            af[ms] = *(const half8*)(&Als[(wm + ms * 16 + lc) * BK + lq * 8]);
#pragma unroll
        for (int ns = 0; ns < 4; ++ns) {
            half8 bd = *(const half8*)(&Bd[(lq * 128 + wn + ns * 16 + lc) * 8]);
#pragma unroll
            for (int ms = 0; ms < 4; ++ms)
                acc[ms][ns] = __builtin_amdgcn_mfma_f32_16x16x32_f16(af[ms], bd, acc[ms][ns], 0, 0, 0);
        }
        __syncthreads();
    }

#pragma unroll
    for (int ms = 0; ms < 4; ++ms) {
#pragma unroll
        for (int r = 0; r < 4; ++r) {
            int row = wm + ms * 16 + lq * 4 + r;
            int id = rid[row];
            if (id >= 0) {
                int tok = id >> 1;
                float w = rw[row];
                float* orow = out + (size_t)tok * D + n0;
#pragma unroll
                for (int ns = 0; ns < 4; ++ns)
                    atomicAdd(&orow[wn + ns * 16 + lc], acc[ms][ns][r] * w);
            }
        }
    }
}

extern "C" void kernel_launch(void* const* d_in, const int* in_sizes, int n_in,
                              void* d_out, int out_size, void* d_ws, size_t ws_size,
                              hipStream_t stream) {
    const float* x  = (const float*)d_in[0];
    const float* gw = (const float*)d_in[1];
    const float* wg = (const float*)d_in[2];
    const float* wu = (const float*)d_in[3];
    const float* wd = (const float*)d_in[4];
    float* out = (float*)d_out;

    char* ws = (char*)d_ws;
    const size_t FAST_NEED = 265356288ull;

    if (ws_size >= FAST_NEED) {
        int*      counts = (int*)(ws);
        int*      ids    = (int*)(ws + 1024);
        float*    wts    = (float*)(ws + 525312);
        float*    wtk    = (float*)(ws + 1049600);
        _Float16* xb     = (_Float16*)(ws + 1115136);
        _Float16* hbuf   = (_Float16*)(ws + 34669568);
        _Float16* wgt    = (_Float16*)(ws + 80806912);
        _Float16* wut    = (_Float16*)(ws + 173081600);
        _Float16* wdt    = wgt;                       // alias: used after gateup
        _Float16* part   = wut;                       // alias: used after gateup

        hipMemsetAsync(counts, 0, 1024, stream);
        router_kernel<<<dim3(NTOK / 4), dim3(256), 0, stream>>>(x, gw, xb, counts, ids, wts, wtk);
        transpose_cvt_kernel<<<dim3(D / 64, I_DIM / 64, E_NUM), dim3(256), 0, stream>>>(wg, wgt, D, I_DIM);
        transpose_cvt_kernel<<<dim3(D / 64, I_DIM / 64, E_NUM), dim3(256), 0, stream>>>(wu, wut, D, I_DIM);
        moe_gateup_f16<<<dim3(176 * 64), dim3(256), 0, stream>>>(xb, wgt, wut, counts, ids, hbuf);
        transpose_cvt_kernel<<<dim3(I_DIM / 64, D / 64, E_NUM), dim3(256), 0, stream>>>(wd, wdt, I_DIM, D);
        moe_down_f16<<<dim3(256 * 64), dim3(256), 0, stream>>>(hbuf, wdt, counts, ids, part);
        combine_kernel<<<dim3(NTOK), dim3(256), 0, stream>>>(part, wtk, out);
    } else {
        // fallback: round-1 path (fp32 weights on the fly)
        int*      counts = (int*)(ws);
        int*      ids    = (int*)(ws + 1024);
        float*    wts    = (float*)(ws + 525312);
        _Float16* xb     = (_Float16*)(ws + 1049600);
        _Float16* hbuf   = (_Float16*)(ws + 34604032);
        float*    wtk    = (float*)(ws + 80741376);

        hipMemsetAsync(counts, 0, 1024, stream);
        hipMemsetAsync(d_out, 0, (size_t)out_size * sizeof(float), stream);
        router_kernel<<<dim3(NTOK / 4), dim3(256), 0, stream>>>(x, gw, xb, counts, ids, wts, wtk);
        moe_gateup_old<<<dim3(64, I_DIM / 128, E_NUM), dim3(256), 0, stream>>>(xb, wg, wu, counts, ids, hbuf);
        moe_down_old<<<dim3(64, D / 128, E_NUM), dim3(256), 0, stream>>>(hbuf, wd, counts, ids, wts, out);
    }
}

// Round 3
// 1180.092 us; speedup vs baseline: 1.0191x; 1.0191x over previous
//
#include <hip/hip_runtime.h>

#define D 2048
#define I_DIM 1408
#define E_NUM 16
#define NTOK 8192
#define BK 32
#define BK2 64

typedef _Float16 half8 __attribute__((ext_vector_type(8)));
typedef float float4v __attribute__((ext_vector_type(4)));

// async global->LDS, 16B per lane; LDS dest = base + lane*16 (linear!)
#define GLL16(gp, lp)                                                        \
    __builtin_amdgcn_global_load_lds(                                        \
        (const __attribute__((address_space(1))) void*)(gp),                 \
        (__attribute__((address_space(3))) void*)(lp), 16, 0, 0)

// ---------------- workspace layout (bytes) ----------------
// counts @0 (1024) | ids @1024 (512K) | wts @525312 (512K) | wtk @1049600 (64K)
// xb @1115136 (32M) | h @34669568 (44M) | wgt @80806912 (88M) | wut @173081600 (88M)
// tier-B: wdt aliases wgt (after gateup) | part aliases wut (after gateup); NEED_B = 265356288
// tier-A: + separate wdt @265356288 (88M); NEED_A = 357630976 (part still aliases wut)

// ---------------- router body (device) ----------------
__device__ __forceinline__ void router_body(
    int t, const float* __restrict__ x, const float* __restrict__ gw,
    _Float16* __restrict__ xb, int* __restrict__ counts,
    int* __restrict__ ids, float* __restrict__ wts, float* __restrict__ wtk)
{
    int lane = threadIdx.x & 63;
    const float* xr = x + (size_t)t * D;

    float acc[E_NUM];
#pragma unroll
    for (int e = 0; e < E_NUM; ++e) acc[e] = 0.f;

#pragma unroll 4
    for (int i = 0; i < D / 64; ++i) {
        int d = lane + i * 64;
        float xv = xr[d];
        xb[(size_t)t * D + d] = (_Float16)xv;
#pragma unroll
        for (int e = 0; e < E_NUM; ++e)
            acc[e] = fmaf(xv, gw[e * D + d], acc[e]);
    }
#pragma unroll
    for (int e = 0; e < E_NUM; ++e) {
        float v = acc[e];
#pragma unroll
        for (int m = 32; m >= 1; m >>= 1) v += __shfl_xor(v, m, 64);
        acc[e] = v;
    }
    if (lane == 0) {
        int e1 = 0; float l1 = acc[0];
#pragma unroll
        for (int e = 1; e < E_NUM; ++e)
            if (acc[e] > l1) { l1 = acc[e]; e1 = e; }
        int e2 = -1; float l2 = -3.0e38f;
#pragma unroll
        for (int e = 0; e < E_NUM; ++e) {
            if (e == e1) continue;
            if (acc[e] > l2) { l2 = acc[e]; e2 = e; }
        }
        float w1 = 1.f / (1.f + expf(l2 - l1));
        float w2 = 1.f - w1;
        int s1 = atomicAdd(&counts[e1], 1);
        ids[e1 * NTOK + s1] = t * 2;     wts[e1 * NTOK + s1] = w1;
        int s2 = atomicAdd(&counts[e2], 1);
        ids[e2 * NTOK + s2] = t * 2 + 1; wts[e2 * NTOK + s2] = w2;
        wtk[t * 2] = w1; wtk[t * 2 + 1] = w2;
    }
}

// ---------------- transpose tile body (device): src fp32 [E][K][N] -> dst fp16 [E][N][K] ----------------
// fp32 LDS tile [64][65]: +1 pad -> both phases 2-way bank access (free).
__device__ __forceinline__ void transpose_tile(
    const float* __restrict__ src, _Float16* __restrict__ dst,
    int K, int N, int k0, int n0, int e, float (*T)[65])
{
    const float* s = src + (size_t)e * K * N + (size_t)k0 * N + n0;
    _Float16* d = dst + (size_t)e * N * K + (size_t)n0 * K + k0;
    int tid = threadIdx.x;
    int kl = tid >> 4;          // 0..15
    int n4 = (tid & 15) * 4;    // 0..60
#pragma unroll
    for (int p = 0; p < 4; ++p) {
        int k = p * 16 + kl;
        float4 v = *(const float4*)(s + (size_t)k * N + n4);
        T[n4 + 0][k] = v.x;
        T[n4 + 1][k] = v.y;
        T[n4 + 2][k] = v.z;
        T[n4 + 3][k] = v.w;
    }
    __syncthreads();
    int nl = tid >> 3;          // 0..31
    int kc = (tid & 7) * 8;     // 0..56
#pragma unroll
    for (int q = 0; q < 2; ++q) {
        int n = q * 32 + nl;
        half8 v;
#pragma unroll
        for (int j = 0; j < 8; ++j) v[j] = (_Float16)T[n][kc + j];
        *(half8*)(d + (size_t)n * K + kc) = v;
    }
}

// ---------------- fused prep: router + transpose(wg) + transpose(wu) [+ transpose(wd)] ----------------
// block ranges: [0,2048) router | [2048,13312) wg | [13312,24576) wu | [24576,35840) wd
// tier-B launches only the first 24576 blocks (wd handled by standalone kernel after gateup).
#define PREP_R   2048
#define PREP_TS  11264          // 32*22*16
__global__ __launch_bounds__(256) void prep_kernel(
    const float* __restrict__ x, const float* __restrict__ gw,
    _Float16* __restrict__ xb, int* __restrict__ counts,
    int* __restrict__ ids, float* __restrict__ wts, float* __restrict__ wtk,
    const float* __restrict__ wg, _Float16* __restrict__ wgt,
    const float* __restrict__ wu, _Float16* __restrict__ wut,
    const float* __restrict__ wd, _Float16* __restrict__ wdt)
{
    __shared__ float T[64][65];
    int b = blockIdx.x;
    if (b < PREP_R) {
        router_body(b * 4 + (threadIdx.x >> 6), x, gw, xb, counts, ids, wts, wtk);
        return;
    }
    b -= PREP_R;
    if (b < PREP_TS) {
        // wg: K=D(32 tiles), N=I_DIM(22 tiles)
        int bx = b % 32, by = (b / 32) % 22, e = b / 704;
        transpose_tile(wg, wgt, D, I_DIM, bx * 64, by * 64, e, T);
        return;
    }
    b -= PREP_TS;
    if (b < PREP_TS) {
        int bx = b % 32, by = (b / 32) % 22, e = b / 704;
        transpose_tile(wu, wut, D, I_DIM, bx * 64, by * 64, e, T);
        return;
    }
    b -= PREP_TS;
    // wd: K=I_DIM(22 tiles), N=D(32 tiles)
    int bx = b % 22, by = (b / 22) % 32, e = b / 704;
    transpose_tile(wd, wdt, I_DIM, D, bx * 64, by * 64, e, T);
}

// ---------------- standalone transpose (tier-B wd path) ----------------
__global__ __launch_bounds__(256) void transpose_cvt_kernel(
    const float* __restrict__ src, _Float16* __restrict__ dst, int K, int N)
{
    __shared__ float T[64][65];
    int e = blockIdx.z;
    transpose_tile(src, dst, K, N, blockIdx.x * 64, blockIdx.y * 64, e, T);
}

// ---------------- fast gate+up: BK2=64, XOR-swizzled LDS (linear dest + pre-swizzled src) ----------------
__global__ __launch_bounds__(256, 2) void moe_gateup_f16(
    const _Float16* __restrict__ xb,
    const _Float16* __restrict__ wgt, const _Float16* __restrict__ wut,
    const int* __restrict__ counts, const int* __restrict__ ids,
    _Float16* __restrict__ h)
{
    int b = blockIdx.x;
    int g = b % 176;                 // n_tile (11) x expert (16)
    int m0 = (b / 176) * 128;        // groups spaced 176 apart -> same XCD
    int e = g / 11;
    int n0 = (g % 11) * 128;
    int cnt = counts[e];
    if (m0 >= cnt) return;

    __shared__ __align__(16) _Float16 Als[128 * BK2];
    __shared__ __align__(16) _Float16 Bg[128 * BK2];
    __shared__ __align__(16) _Float16 Bu[128 * BK2];
    __shared__ int rid[128];

    int tid = threadIdx.x;
    if (tid < 128) {
        int slot = m0 + tid;
        rid[tid] = (slot < cnt) ? ids[e * NTOK + slot] : -1;
    }
    __syncthreads();

    const _Float16* wgE = wgt + (size_t)e * I_DIM * D;
    const _Float16* wuE = wut + (size_t)e * I_DIM * D;

    int wave = tid >> 6, lane = tid & 63;
    int wm = (wave & 1) * 64, wn = (wave >> 1) * 64;
    int lc = lane & 15, lq = lane >> 4;
    int lr8 = lane >> 3;                     // sub-row 0..7 within an 8-row chunk
    int gseg = ((lane & 7) ^ lr8) * 8;       // swizzled source offset (halves)

    float4v accG[4][4], accU[4][4];
#pragma unroll
    for (int a = 0; a < 4; ++a)
#pragma unroll
        for (int c = 0; c < 4; ++c) {
            accG[a][c] = (float4v){0.f, 0.f, 0.f, 0.f};
            accU[a][c] = (float4v){0.f, 0.f, 0.f, 0.f};
        }

    for (int k0 = 0; k0 < D; k0 += BK2) {
#pragma unroll
        for (int c = 0; c < 4; ++c) {
            int r0 = wave * 32 + c * 8;      // wave-uniform LDS base (8 rows = 1KB)
            int row = r0 + lr8;
            int id = rid[row];
            int tr = (id >= 0) ? (id >> 1) : 0;
            GLL16(xb + (size_t)tr * D + k0 + gseg, &Als[r0 * BK2]);
            GLL16(wgE + (size_t)(n0 + row) * D + k0 + gseg, &Bg[r0 * BK2]);
            GLL16(wuE + (size_t)(n0 + row) * D + k0 + gseg, &Bu[r0 * BK2]);
        }
        __syncthreads();

#pragma unroll
        for (int ks = 0; ks < 2; ++ks) {
            half8 af[4];
#pragma unroll
            for (int ms = 0; ms < 4; ++ms) {
                int row = wm + ms * 16 + lc;
                int s = (ks * 4 + lq) ^ (row & 7);
                af[ms] = *(const half8*)(&Als[row * BK2 + s * 8]);
            }
#pragma unroll
            for (int ns = 0; ns < 4; ++ns) {
                int row = wn + ns * 16 + lc;
                int s = (ks * 4 + lq) ^ (row & 7);
                half8 bg = *(const half8*)(&Bg[row * BK2 + s * 8]);
                half8 bu = *(const half8*)(&Bu[row * BK2 + s * 8]);
#pragma unroll
                for (int ms = 0; ms < 4; ++ms) {
                    accG[ms][ns] = __builtin_amdgcn_mfma_f32_16x16x32_f16(af[ms], bg, accG[ms][ns], 0, 0, 0);
                    accU[ms][ns] = __builtin_amdgcn_mfma_f32_16x16x32_f16(af[ms], bu, accU[ms][ns], 0, 0, 0);
                }
            }
        }
        __syncthreads();
    }

#pragma unroll
    for (int ms = 0; ms < 4; ++ms) {
#pragma unroll
        for (int r = 0; r < 4; ++r) {
            int row = wm + ms * 16 + lq * 4 + r;
            int id = rid[row];
            if (id >= 0) {
                _Float16* hr = h + (size_t)id * I_DIM + n0;
#pragma unroll
                for (int ns = 0; ns < 4; ++ns) {
                    float gv = accG[ms][ns][r];
                    float uv = accU[ms][ns][r];
                    float sv = gv / (1.f + expf(-gv)) * uv;
                    hr[wn + ns * 16 + lc] = (_Float16)sv;
                }
            }
        }
    }
}

// ---------------- fast down: BK2=64, swizzle + 2-phase double-buffered prefetch ----------------
// T3-minimum: issue next tile's global_load_lds BEFORE this tile's MFMA phase; the single
// vmcnt-drain at the closing barrier then overlaps HBM latency with compute.
// LDS = 2*(16K+16K)+rid = 66KB -> still 2 blocks/CU.
__global__ __launch_bounds__(256, 2) void moe_down_f16(
    const _Float16* __restrict__ h, const _Float16* __restrict__ wdt,
    const int* __restrict__ counts, const int* __restrict__ ids,
    _Float16* __restrict__ part)
{
    int b = blockIdx.x;
    int g = b % 256;                 // n_tile (16) x expert (16)
    int m0 = (b / 256) * 128;        // spaced 256 apart -> same XCD
    int e = g >> 4;
    int n0 = (g & 15) * 128;
    int cnt = counts[e];
    if (m0 >= cnt) return;

    __shared__ __align__(16) _Float16 Als[2][128 * BK2];
    __shared__ __align__(16) _Float16 Bd[2][128 * BK2];
    __shared__ int rid[128];

    int tid = threadIdx.x;
    if (tid < 128) {
        int slot = m0 + tid;
        rid[tid] = (slot < cnt) ? ids[e * NTOK + slot] : -1;
    }
    __syncthreads();

    const _Float16* wdE = wdt + (size_t)e * D * I_DIM;

    int wave = tid >> 6, lane = tid & 63;
    int wm = (wave & 1) * 64, wn = (wave >> 1) * 64;
    int lc = lane & 15, lq = lane >> 4;
    int lr8 = lane >> 3;
    int gseg = ((lane & 7) ^ lr8) * 8;

    float4v acc[4][4];
#pragma unroll
    for (int a = 0; a < 4; ++a)
#pragma unroll
        for (int c = 0; c < 4; ++c)
            acc[a][c] = (float4v){0.f, 0.f, 0.f, 0.f};

#define DOWN_STAGE(buf, kk0)                                                  \
    do {                                                                      \
        _Pragma("unroll")                                                     \
        for (int c = 0; c < 4; ++c) {                                         \
            int r0 = wave * 32 + c * 8;                                       \
            int row = r0 + lr8;                                               \
            int id = rid[row];                                                \
            int tr = (id >= 0) ? id : 0;                                      \
            GLL16(h + (size_t)tr * I_DIM + (kk0) + gseg, &Als[buf][r0 * BK2]);\
            GLL16(wdE + (size_t)(n0 + row) * I_DIM + (kk0) + gseg,            \
                  &Bd[buf][r0 * BK2]);                                        \
        }                                                                     \
    } while (0)

    DOWN_STAGE(0, 0);
    __syncthreads();                 // vmcnt(0) drained here: buf0 ready

    int cur = 0;
    for (int k0 = 0; k0 < I_DIM; k0 += BK2) {
        int nxt = k0 + BK2;
        if (nxt < I_DIM) DOWN_STAGE(cur ^ 1, nxt);   // async, overlaps MFMA below

#pragma unroll
        for (int ks = 0; ks < 2; ++ks) {
            half8 af[4];
#pragma unroll
            for (int ms = 0; ms < 4; ++ms) {
                int row = wm + ms * 16 + lc;
                int s = (ks * 4 + lq) ^ (row & 7);
                af[ms] = *(const half8*)(&Als[cur][row * BK2 + s * 8]);
            }
#pragma unroll
            for (int ns = 0; ns < 4; ++ns) {
                int row = wn + ns * 16 + lc;
                int s = (ks * 4 + lq) ^ (row & 7);
                half8 bd = *(const half8*)(&Bd[cur][row * BK2 + s * 8]);
#pragma unroll
                for (int ms = 0; ms < 4; ++ms)
                    acc[ms][ns] = __builtin_amdgcn_mfma_f32_16x16x32_f16(af[ms], bd, acc[ms][ns], 0, 0, 0);
            }
        }
        __syncthreads();             // drains next-tile loads (already in flight) + read fences
        cur ^= 1;
    }
#undef DOWN_STAGE

#pragma unroll
    for (int ms = 0; ms < 4; ++ms) {
#pragma unroll
        for (int r = 0; r < 4; ++r) {
            int row = wm + ms * 16 + lq * 4 + r;
            int id = rid[row];
            if (id >= 0) {
                _Float16* pr = part + (size_t)id * D + n0;
#pragma unroll
                for (int ns = 0; ns < 4; ++ns)
                    pr[wn + ns * 16 + lc] = (_Float16)acc[ms][ns][r];
            }
        }
    }
}

// ---------------- combine: out[t] = w1*part[2t] + w2*part[2t+1] ----------------
__global__ __launch_bounds__(256) void combine_kernel(
    const _Float16* __restrict__ part, const float* __restrict__ wtk,
    float* __restrict__ out)
{
    int t = blockIdx.x;
    int tid = threadIdx.x;
    float w1 = wtk[2 * t], w2 = wtk[2 * t + 1];
    const _Float16* p1 = part + (size_t)(2 * t) * D;
    const _Float16* p2 = p1 + D;
    float* o = out + (size_t)t * D;
    int i = tid * 8;
    half8 a = *(const half8*)(p1 + i);
    half8 bvec = *(const half8*)(p2 + i);
#pragma unroll
    for (int j = 0; j < 8; ++j)
        o[i + j] = w1 * (float)a[j] + w2 * (float)bvec[j];
}

// ================= fallback (round-1) kernels, fp32 weights =================
__global__ __launch_bounds__(256) void router_kernel(
    const float* __restrict__ x, const float* __restrict__ gw,
    _Float16* __restrict__ xb, int* __restrict__ counts,
    int* __restrict__ ids, float* __restrict__ wts, float* __restrict__ wtk)
{
    router_body(blockIdx.x * 4 + (threadIdx.x >> 6), x, gw, xb, counts, ids, wts, wtk);
}

__global__ __launch_bounds__(256, 2) void moe_gateup_old(
    const _Float16* __restrict__ xb,
    const float* __restrict__ wg, const float* __restrict__ wu,
    const int* __restrict__ counts, const int* __restrict__ ids,
    _Float16* __restrict__ h)
{
    int e = blockIdx.z;
    int cnt = counts[e];
    int m0 = blockIdx.x * 128;
    if (m0 >= cnt) return;
    int n0 = blockIdx.y * 128;

    __shared__ __align__(16) _Float16 Als[128 * BK];
    __shared__ __align__(16) _Float16 Bg[BK * 128];
    __shared__ __align__(16) _Float16 Bu[BK * 128];
    __shared__ int rid[128];

    int tid = threadIdx.x;
    if (tid < 128) {
        int slot = m0 + tid;
        rid[tid] = (slot < cnt) ? ids[e * NTOK + slot] : -1;
    }
    __syncthreads();

    const float* wgE = wg + (size_t)e * D * I_DIM;
    const float* wuE = wu + (size_t)e * D * I_DIM;

    int wave = tid >> 6, lane = tid & 63;
    int wm = (wave & 1) * 64, wn = (wave >> 1) * 64;
    int lc = lane & 15, lq = lane >> 4;

    float4v accG[4][4], accU[4][4];
#pragma unroll
    for (int a = 0; a < 4; ++a)
#pragma unroll
        for (int c = 0; c < 4; ++c) {
            accG[a][c] = (float4v){0.f, 0.f, 0.f, 0.f};
            accU[a][c] = (float4v){0.f, 0.f, 0.f, 0.f};
        }

    int nn = tid & 127;
    int kb2 = tid >> 7;

    for (int k0 = 0; k0 < D; k0 += BK) {
#pragma unroll
        for (int cc = 0; cc < 2; ++cc) {
            int c = tid + cc * 256;
            int row = c >> 2, kc = c & 3;
            int id = rid[row];
            uint4 v = {0u, 0u, 0u, 0u};
            if (id >= 0)
                v = *(const uint4*)(xb + (size_t)(id >> 1) * D + k0 + kc * 8);
            *(uint4*)(&Als[row * BK + kc * 8]) = v;
        }
#pragma unroll
        for (int kk = 0; kk < 2; ++kk) {
            int kb = kb2 * 2 + kk;
            const float* pg = wgE + (size_t)(k0 + kb * 8) * I_DIM + n0 + nn;
            const float* pu = wuE + (size_t)(k0 + kb * 8) * I_DIM + n0 + nn;
            half8 hg, hu;
#pragma unroll
            for (int j = 0; j < 8; ++j) {
                hg[j] = (_Float16)pg[(size_t)j * I_DIM];
                hu[j] = (_Float16)pu[(size_t)j * I_DIM];
            }
            *(half8*)(&Bg[(kb * 128 + nn) * 8]) = hg;
            *(half8*)(&Bu[(kb * 128 + nn) * 8]) = hu;
        }
        __syncthreads();

        half8 af[4];
#pragma unroll
        for (int ms = 0; ms < 4; ++ms)
            af[ms] = *(const half8*)(&Als[(wm + ms * 16 + lc) * BK + lq * 8]);
#pragma unroll
        for (int ns = 0; ns < 4; ++ns) {
            half8 bg = *(const half8*)(&Bg[(lq * 128 + wn + ns * 16 + lc) * 8]);
            half8 bu = *(const half8*)(&Bu[(lq * 128 + wn + ns * 16 + lc) * 8]);
#pragma unroll
            for (int ms = 0; ms < 4; ++ms) {
                accG[ms][ns] = __builtin_amdgcn_mfma_f32_16x16x32_f16(af[ms], bg, accG[ms][ns], 0, 0, 0);
                accU[ms][ns] = __builtin_amdgcn_mfma_f32_16x16x32_f16(af[ms], bu, accU[ms][ns], 0, 0, 0);
            }
        }
        __syncthreads();
    }

#pragma unroll
    for (int ms = 0; ms < 4; ++ms) {
#pragma unroll
        for (int r = 0; r < 4; ++r) {
            int row = wm + ms * 16 + lq * 4 + r;
            int id = rid[row];
            if (id >= 0) {
                _Float16* hr = h + (size_t)id * I_DIM + n0;
#pragma unroll
                for (int ns = 0; ns < 4; ++ns) {
                    float gv = accG[ms][ns][r];
                    float uv = accU[ms][ns][r];
                    float sv = gv / (1.f + expf(-gv)) * uv;
                    hr[wn + ns * 16 + lc] = (_Float16)sv;
                }
            }
        }
    }
}

__global__ __launch_bounds__(256, 2) void moe_down_old(
    const _Float16* __restrict__ h, const float* __restrict__ wd,
    const int* __restrict__ counts, const int* __restrict__ ids,
    const float* __restrict__ wts, float* __restrict__ out)
{
    int e = blockIdx.z;
    int cnt = counts[e];
    int m0 = blockIdx.x * 128;
    if (m0 >= cnt) return;
    int n0 = blockIdx.y * 128;

    __shared__ __align__(16) _Float16 Als[128 * BK];
    __shared__ __align__(16) _Float16 Bd[BK * 128];
    __shared__ int rid[128];
    __shared__ float rw[128];

    int tid = threadIdx.x;
    if (tid < 128) {
        int slot = m0 + tid;
        int ok = slot < cnt;
        rid[tid] = ok ? ids[e * NTOK + slot] : -1;
        rw[tid]  = ok ? wts[e * NTOK + slot] : 0.f;
    }
    __syncthreads();

    const float* wdE = wd + (size_t)e * I_DIM * D;

    int wave = tid >> 6, lane = tid & 63;
    int wm = (wave & 1) * 64, wn = (wave >> 1) * 64;
    int lc = lane & 15, lq = lane >> 4;

    float4v acc[4][4];
#pragma unroll
    for (int a = 0; a < 4; ++a)
#pragma unroll
        for (int c = 0; c < 4; ++c)
            acc[a][c] = (float4v){0.f, 0.f, 0.f, 0.f};

    int nn = tid & 127;
    int kb2 = tid >> 7;

    for (int k0 = 0; k0 < I_DIM; k0 += BK) {
#pragma unroll
        for (int cc = 0; cc < 2; ++cc) {
            int c = tid + cc * 256;
            int row = c >> 2, kc = c & 3;
            int id = rid[row];
            uint4 v = {0u, 0u, 0u, 0u};
            if (id >= 0)
                v = *(const uint4*)(h + (size_t)id * I_DIM + k0 + kc * 8);
            *(uint4*)(&Als[row * BK + kc * 8]) = v;
        }
#pragma unroll
        for (int kk = 0; kk < 2; ++kk) {
            int kb = kb2 * 2 + kk;
            const float* pd = wdE + (size_t)(k0 + kb * 8) * D + n0 + nn;
            half8 hd;
#pragma unroll
            for (int j = 0; j < 8; ++j)
                hd[j] = (_Float16)pd[(size_t)j * D];
            *(half8*)(&Bd[(kb * 128 + nn) * 8]) = hd;
        }
        __syncthreads();

        half8 af[4];
#pragma unroll
        for (int ms = 0; ms < 4; ++ms)
            af[ms] = *(const half8*)(&Als[(wm + ms * 16 + lc) * BK + lq * 8]);
#pragma unroll
        for (int ns = 0; ns < 4; ++ns) {
            half8 bd = *(const half8*)(&Bd[(lq * 128 + wn + ns * 16 + lc) * 8]);
#pragma unroll
            for (int ms = 0; ms < 4; ++ms)
                acc[ms][ns] = __builtin_amdgcn_mfma_f32_16x16x32_f16(af[ms], bd, acc[ms][ns], 0, 0, 0);
        }
        __syncthreads();
    }

#pragma unroll
    for (int ms = 0; ms < 4; ++ms) {
#pragma unroll
        for (int r = 0; r < 4; ++r) {
            int row = wm + ms * 16 + lq * 4 + r;
            int id = rid[row];
            if (id >= 0) {
                int tok = id >> 1;
                float w = rw[row];
                float* orow = out + (size_t)tok * D + n0;
#pragma unroll
                for (int ns = 0; ns < 4; ++ns)
                    atomicAdd(&orow[wn + ns * 16 + lc], acc[ms][ns][r] * w);
            }
        }
    }
}

extern "C" void kernel_launch(void* const* d_in, const int* in_sizes, int n_in,
                              void* d_out, int out_size, void* d_ws, size_t ws_size,
                              hipStream_t stream) {
    const float* x  = (const float*)d_in[0];
    const float* gw = (const float*)d_in[1];
    const float* wg = (const float*)d_in[2];
    const float* wu = (const float*)d_in[3];
    const float* wd = (const float*)d_in[4];
    float* out = (float*)d_out;

    char* ws = (char*)d_ws;
    const size_t NEED_B = 265356288ull;
    const size_t NEED_A = 357630976ull;   // + separate wdt (88M)

    if (ws_size >= NEED_B) {
        int*      counts = (int*)(ws);
        int*      ids    = (int*)(ws + 1024);
        float*    wts    = (float*)(ws + 525312);
        float*    wtk    = (float*)(ws + 1049600);
        _Float16* xb     = (_Float16*)(ws + 1115136);
        _Float16* hbuf   = (_Float16*)(ws + 34669568);
        _Float16* wgt    = (_Float16*)(ws + 80806912);
        _Float16* wut    = (_Float16*)(ws + 173081600);
        _Float16* part   = wut;                       // alias: used after gateup

        hipMemsetAsync(counts, 0, 1024, stream);

        if (ws_size >= NEED_A) {
            // tier-A: separate wdt -> single fused prep (router + all 3 transposes)
            _Float16* wdt = (_Float16*)(ws + 265356288);
            prep_kernel<<<dim3(PREP_R + 3 * PREP_TS), dim3(256), 0, stream>>>(
                x, gw, xb, counts, ids, wts, wtk, wg, wgt, wu, wut, wd, wdt);
            moe_gateup_f16<<<dim3(176 * 64), dim3(256), 0, stream>>>(xb, wgt, wut, counts, ids, hbuf);
            moe_down_f16<<<dim3(256 * 64), dim3(256), 0, stream>>>(hbuf, wdt, counts, ids, part);
        } else {
            // tier-B: wdt aliases wgt -> wd transpose must follow gateup
            _Float16* wdt = wgt;
            prep_kernel<<<dim3(PREP_R + 2 * PREP_TS), dim3(256), 0, stream>>>(
                x, gw, xb, counts, ids, wts, wtk, wg, wgt, wu, wut, wd, wdt);
            moe_gateup_f16<<<dim3(176 * 64), dim3(256), 0, stream>>>(xb, wgt, wut, counts, ids, hbuf);
            transpose_cvt_kernel<<<dim3(I_DIM / 64, D / 64, E_NUM), dim3(256), 0, stream>>>(wd, wdt, I_DIM, D);
            moe_down_f16<<<dim3(256 * 64), dim3(256), 0, stream>>>(hbuf, wdt, counts, ids, part);
        }
        combine_kernel<<<dim3(NTOK), dim3(256), 0, stream>>>(part, wtk, out);
    } else {
        // fallback: round-1 path (fp32 weights on the fly)
        int*      counts = (int*)(ws);
        int*      ids    = (int*)(ws + 1024);
        float*    wts    = (float*)(ws + 525312);
        _Float16* xb     = (_Float16*)(ws + 1049600);
        _Float16* hbuf   = (_Float16*)(ws + 34604032);
        float*    wtk    = (float*)(ws + 80741376);

        hipMemsetAsync(counts, 0, 1024, stream);
        hipMemsetAsync(d_out, 0, (size_t)out_size * sizeof(float), stream);
        router_kernel<<<dim3(NTOK / 4), dim3(256), 0, stream>>>(x, gw, xb, counts, ids, wts, wtk);
        moe_gateup_old<<<dim3(64, I_DIM / 128, E_NUM), dim3(256), 0, stream>>>(xb, wg, wu, counts, ids, hbuf);
        moe_down_old<<<dim3(64, D / 128, E_NUM), dim3(256), 0, stream>>>(hbuf, wd, counts, ids, wts, out);
    }
}